// Round 1
// baseline (25.618 us; speedup 1.0000x reference)
//
#include <hip/hip_runtime.h>

// RoPE: x (B=8, S=16384, D=128) f32, cos/sin tables (16384, 64) f32,
// token_positions (16384,) i32. Interleaved pair layout:
// out[2i]   = cos[i]*x[2i] - sin[i]*x[2i+1]
// out[2i+1] = sin[i]*x[2i] + cos[i]*x[2i+1]

#define S_LEN 16384
#define DK    128
#define NF4_PER_ROW (DK / 4)   // 32 float4 per row

__global__ __launch_bounds__(256) void rope_f32_kernel(
    const float4* __restrict__ x,
    const float2* __restrict__ cos_tab,   // rows of 64 f32 = 32 float2
    const float2* __restrict__ sin_tab,
    const int*    __restrict__ tok_pos,
    float4*       __restrict__ out)
{
    const int t   = blockIdx.x * blockDim.x + threadIdx.x;
    const int j   = t & (NF4_PER_ROW - 1);     // float4 index within row
    const int row = t >> 5;                    // b*S + s
    const int s   = row & (S_LEN - 1);
    const int pos = tok_pos[s];

    const float2 c  = cos_tab[pos * (DK / 4) + j];  // 2 pairs -> 2 cos
    const float2 sn = sin_tab[pos * (DK / 4) + j];
    const float4 v  = x[t];

    float4 o;
    o.x = c.x * v.x - sn.x * v.y;
    o.y = sn.x * v.x + c.x * v.y;
    o.z = c.y * v.z - sn.y * v.w;
    o.w = sn.y * v.z + c.y * v.w;
    out[t] = o;
}

extern "C" void kernel_launch(void* const* d_in, const int* in_sizes, int n_in,
                              void* d_out, int out_size, void* d_ws, size_t ws_size,
                              hipStream_t stream) {
    const float4* x   = (const float4*)d_in[0];
    const float2* ct  = (const float2*)d_in[1];
    const float2* st  = (const float2*)d_in[2];
    const int*    tp  = (const int*)d_in[3];
    float4*       out = (float4*)d_out;

    const int n_f4   = out_size / 4;           // 8*16384*128/4 = 4,194,304
    const int block  = 256;
    const int grid   = (n_f4 + block - 1) / block;   // 16384

    rope_f32_kernel<<<grid, block, 0, stream>>>(x, ct, st, tp, out);
}